// Round 2
// baseline (307.358 us; speedup 1.0000x reference)
//
#include <hip/hip_runtime.h>
#include <cstdint>
#include <cstddef>

#define BM 128
#define BN 128
#define BK 32

using bf16x8 = __attribute__((ext_vector_type(8))) short;
using f32x4  = __attribute__((ext_vector_type(4))) float;

__device__ __forceinline__ unsigned short f2bf(float f) {
  unsigned int u = __builtin_bit_cast(unsigned int, f);
  u += 0x7FFFu + ((u >> 16) & 1u);   // round-to-nearest-even
  return (unsigned short)(u >> 16);
}
__device__ __forceinline__ float bf2f(unsigned int h16) {
  unsigned int u = h16 << 16;
  return __builtin_bit_cast(float, u);
}

__device__ __forceinline__ void gl_lds16(const void* g, void* l) {
  __builtin_amdgcn_global_load_lds(
      (const __attribute__((address_space(1))) unsigned int*)g,
      (__attribute__((address_space(3))) unsigned int*)l,
      16, 0, 0);
}

// C[m,n] = sum_{k in [z*KC,(z+1)*KC)} A[m,k]*B[n,k]  (A: MxK, B: NxK, bf16 row-major)
// MODE 0: E = exp(scale[n]/(sqrt(max(x2[m]-2c+p2[n],0))+0.1)) -> bf16; row-sums atomically into aux3
// MODE 1: bf16 store of c + bias[n]                  (aux0 = bias, len N)
// MODE 2: bf16 store of c
// MODE 3: unsafeAtomicAdd(outF32[m*N+n], c * aux0[m])   (aux0 = rdenom, split-K)
template<int MODE>
__global__ void gemm_bt(const unsigned short* __restrict__ A,
                        const unsigned short* __restrict__ B,
                        void* __restrict__ Cv,
                        int M, int N, int K, int KC,
                        const float* __restrict__ aux0,
                        const float* __restrict__ aux1,
                        const float* __restrict__ aux2,
                        float* __restrict__ aux3)
{
  __shared__ unsigned short As[BM * BK];
  __shared__ unsigned short Bs[BN * BK];

  const int tid  = threadIdx.x;
  const int lane = tid & 63;
  const int wv   = tid >> 6;
  const int wm   = (wv >> 1) * 64;
  const int wn   = (wv & 1) * 64;
  const int l16  = lane & 15;
  const int quad = lane >> 4;

  const int n0 = blockIdx.x * BN;
  const int m0 = blockIdx.y * BM;
  const int kbeg = blockIdx.z * KC;
  const int kend = kbeg + KC;

  f32x4 acc[4][4];
#pragma unroll
  for (int i = 0; i < 4; ++i)
#pragma unroll
    for (int j = 0; j < 4; ++j) {
      f32x4 z = {0.f, 0.f, 0.f, 0.f};
      acc[i][j] = z;
    }

  const int row0 = tid >> 2;
  const int col8 = (tid & 3) * 8;

  const unsigned short* Ag0 = A + (size_t)(m0 + row0) * K + col8;
  const unsigned short* Ag1 = A + (size_t)(m0 + row0 + 64) * K + col8;
  const unsigned short* Bg0 = B + (size_t)(n0 + row0) * K + col8;
  const unsigned short* Bg1 = B + (size_t)(n0 + row0 + 64) * K + col8;
  unsigned short* Al0 = &As[(size_t)tid * 8];
  unsigned short* Al1 = &As[(size_t)(tid + 256) * 8];
  unsigned short* Bl0 = &Bs[(size_t)tid * 8];
  unsigned short* Bl1 = &Bs[(size_t)(tid + 256) * 8];

  for (int kc = kbeg; kc < kend; kc += BK) {
    __syncthreads();
    gl_lds16(Ag0 + kc, Al0);
    gl_lds16(Ag1 + kc, Al1);
    gl_lds16(Bg0 + kc, Bl0);
    gl_lds16(Bg1 + kc, Bl1);
    __syncthreads();

    bf16x8 af[4], bfr[4];
#pragma unroll
    for (int mi = 0; mi < 4; ++mi)
      af[mi] = *(const bf16x8*)&As[(wm + mi * 16 + l16) * BK + quad * 8];
#pragma unroll
    for (int ni = 0; ni < 4; ++ni)
      bfr[ni] = *(const bf16x8*)&Bs[(wn + ni * 16 + l16) * BK + quad * 8];
#pragma unroll
    for (int mi = 0; mi < 4; ++mi)
#pragma unroll
      for (int ni = 0; ni < 4; ++ni)
        acc[mi][ni] = __builtin_amdgcn_mfma_f32_16x16x32_bf16(af[mi], bfr[ni], acc[mi][ni], 0, 0, 0);
  }

  // ---- epilogue ----
  float p2v[4], scv[4], bnv[4];
  if (MODE == 0) {
#pragma unroll
    for (int ni = 0; ni < 4; ++ni) {
      const int n = n0 + wn + ni * 16 + l16;
      p2v[ni] = aux1[n];
      scv[ni] = aux2[n];
    }
  }
  if (MODE == 1) {
#pragma unroll
    for (int ni = 0; ni < 4; ++ni) bnv[ni] = aux0[n0 + wn + ni * 16 + l16];
  }

#pragma unroll
  for (int mi = 0; mi < 4; ++mi) {
#pragma unroll
    for (int r = 0; r < 4; ++r) {
      const int m = m0 + wm + mi * 16 + quad * 4 + r;
      float rowa = 0.f;
      if (MODE == 0 || MODE == 3) rowa = aux0[m];
      float s = 0.f;
#pragma unroll
      for (int ni = 0; ni < 4; ++ni) {
        const int n = n0 + wn + ni * 16 + l16;
        float v = acc[mi][ni][r];
        if (MODE == 0) {
          float sq   = fmaxf(rowa - 2.0f * v + p2v[ni], 0.0f);
          float dist = sqrtf(sq);
          float e    = __expf(scv[ni] / (dist + 0.1f));
          unsigned short eb = f2bf(e);
          ((unsigned short*)Cv)[(size_t)m * N + n] = eb;
          s += bf2f(eb);                 // sum exactly what we stored
        } else if (MODE == 1) {
          ((unsigned short*)Cv)[(size_t)m * N + n] = f2bf(v + bnv[ni]);
        } else if (MODE == 2) {
          ((unsigned short*)Cv)[(size_t)m * N + n] = f2bf(v);
        } else {
          unsafeAtomicAdd(&((float*)Cv)[(size_t)m * N + n], v * rowa);
        }
      }
      if (MODE == 0) {
        // reduce the 16 lanes (l16) that share this output row, then one atomic
        s += __shfl_down(s, 8);
        s += __shfl_down(s, 4);
        s += __shfl_down(s, 2);
        s += __shfl_down(s, 1);
        if (l16 == 0) unsafeAtomicAdd(&aux3[m], s);
      }
    }
  }
}

// fp32 -> bf16 convert, 4 elems/thread
__global__ void cvt_bf16(const float* __restrict__ in, unsigned short* __restrict__ out, int n4) {
  int i = blockIdx.x * 256 + threadIdx.x;
  if (i < n4) {
    float4 v = ((const float4*)in)[i];
    ushort4 o;
    o.x = f2bf(v.x); o.y = f2bf(v.y); o.z = f2bf(v.z); o.w = f2bf(v.w);
    ((ushort4*)out)[i] = o;
  }
}

// per-row sum of squares, 512 cols, one wave per row, 4 rows/block
__global__ void row_sumsq(const float* __restrict__ X, float* __restrict__ out) {
  const int lane = threadIdx.x & 63;
  const int wv   = threadIdx.x >> 6;
  const int r    = blockIdx.x * 4 + wv;
  const float4 a = *(const float4*)(X + (size_t)r * 512 + lane * 4);
  const float4 b = *(const float4*)(X + (size_t)r * 512 + 256 + lane * 4);
  float s = a.x*a.x + a.y*a.y + a.z*a.z + a.w*a.w
          + b.x*b.x + b.y*b.y + b.z*b.z + b.w*b.w;
#pragma unroll
  for (int off = 32; off > 0; off >>= 1) s += __shfl_down(s, off, 64);
  if (lane == 0) out[r] = s;
}

__global__ void zero_f32(float* __restrict__ p, int n) {
  int i = blockIdx.x * 256 + threadIdx.x;
  if (i < n) p[i] = 0.f;
}

__global__ void recip_f32(const float* __restrict__ in, float* __restrict__ out, int n) {
  int i = blockIdx.x * 256 + threadIdx.x;
  if (i < n) out[i] = 1.0f / in[i];
}

// out[m, e] = b_o[e]  (float4 per thread; 512 cols = 128 float4)
__global__ void init_out(float* __restrict__ out, const float* __restrict__ b_o) {
  int i = blockIdx.x * 256 + threadIdx.x;   // 1M float4
  float4 b = ((const float4*)b_o)[i & 127];
  ((float4*)out)[i] = b;
}

extern "C" void kernel_launch(void* const* d_in, const int* in_sizes, int n_in,
                              void* d_out, int out_size, void* d_ws, size_t ws_size,
                              hipStream_t stream) {
  const float* x         = (const float*)d_in[0];
  const float* positions = (const float*)d_in[1];
  const float* scale     = (const float*)d_in[2];
  const float* w_v       = (const float*)d_in[3];
  const float* b_v       = (const float*)d_in[4];
  const float* w_o       = (const float*)d_in[5];
  const float* b_o       = (const float*)d_in[6];
  float* out = (float*)d_out;

  const int M = 8192, N = 4096, D = 512;

  char* ws = (char*)d_ws;
  unsigned short* Eb  = (unsigned short*)ws; ws += (size_t)M * N * 2;   // exp(interactions) bf16, 64 MB
  unsigned short* v2T = (unsigned short*)ws; ws += (size_t)D * N * 2;   // (values @ w_o^T)^T : (D x N) bf16
  unsigned short* val = (unsigned short*)ws; ws += (size_t)N * D * 2;   // values (N x D) bf16
  unsigned short* xb  = (unsigned short*)ws; ws += (size_t)M * D * 2;   // x bf16
  unsigned short* pb  = (unsigned short*)ws; ws += (size_t)N * D * 2;   // positions bf16
  unsigned short* wvb = (unsigned short*)ws; ws += (size_t)D * D * 2;   // w_v bf16
  unsigned short* wob = (unsigned short*)ws; ws += (size_t)D * D * 2;   // w_o bf16
  float* x2    = (float*)ws; ws += (size_t)M * 4;
  float* p2    = (float*)ws; ws += (size_t)N * 4;
  float* denom = (float*)ws; ws += (size_t)M * 4;
  float* rd    = (float*)ws; ws += (size_t)M * 4;

  // conversions + row norms + inits
  cvt_bf16<<<(M * D / 4 + 255) / 256, 256, 0, stream>>>(x, xb, M * D / 4);
  cvt_bf16<<<(N * D / 4 + 255) / 256, 256, 0, stream>>>(positions, pb, N * D / 4);
  cvt_bf16<<<(D * D / 4 + 255) / 256, 256, 0, stream>>>(w_v, wvb, D * D / 4);
  cvt_bf16<<<(D * D / 4 + 255) / 256, 256, 0, stream>>>(w_o, wob, D * D / 4);
  row_sumsq<<<M / 4, 256, 0, stream>>>(x, x2);
  row_sumsq<<<N / 4, 256, 0, stream>>>(positions, p2);
  zero_f32<<<(M + 255) / 256, 256, 0, stream>>>(denom, M);
  init_out<<<M * D / 4 / 256, 256, 0, stream>>>(out, b_o);

  // values[n,d] = sum_k positions[n,k] w_v[d,k] + b_v[d]
  gemm_bt<1><<<dim3(D / BN, N / BM), 256, 0, stream>>>(
      pb, wvb, val, N, D, D, D, b_v, nullptr, nullptr, nullptr);

  // v2T[e,n] = sum_d w_o[e,d] values[n,d]   (bias b_o folded into init_out)
  gemm_bt<2><<<dim3(N / BN, D / BM), 256, 0, stream>>>(
      wob, val, v2T, D, N, D, D, nullptr, nullptr, nullptr, nullptr);

  // E[m,n] = exp(scale[n]/(dist(m,n)+0.1)); denom[m] += row sums (atomic)
  gemm_bt<0><<<dim3(N / BN, M / BM), 256, 0, stream>>>(
      xb, pb, Eb, M, N, D, D, x2, p2, scale, denom);

  // rd[m] = 1/denom[m]
  recip_f32<<<(M + 255) / 256, 256, 0, stream>>>(denom, rd, M);

  // out[m,e] += rd[m] * sum_n E[m,n] v2T[e,n]   (split-K=4, atomic accumulate)
  gemm_bt<3><<<dim3(D / BN, M / BM, 4), 256, 0, stream>>>(
      Eb, v2T, out, M, D, N, N / 4, rd, nullptr, nullptr, nullptr);
}

// Round 4
// 250.810 us; speedup vs baseline: 1.2255x; 1.2255x over previous
//
#include <hip/hip_runtime.h>
#include <cstdint>
#include <cstddef>

#define BM 128
#define BN 128
#define BK 32

using bf16x8 = __attribute__((ext_vector_type(8))) short;
using f32x4  = __attribute__((ext_vector_type(4))) float;

__device__ __forceinline__ unsigned short f2bf(float f) {
  unsigned int u = __builtin_bit_cast(unsigned int, f);
  u += 0x7FFFu + ((u >> 16) & 1u);   // round-to-nearest-even
  return (unsigned short)(u >> 16);
}
__device__ __forceinline__ float bf2f(unsigned int h16) {
  unsigned int u = h16 << 16;
  return __builtin_bit_cast(float, u);
}

__device__ __forceinline__ void gl_lds16(const void* g, void* l) {
  __builtin_amdgcn_global_load_lds(
      (const __attribute__((address_space(1))) unsigned int*)g,
      (__attribute__((address_space(3))) unsigned int*)l,
      16, 0, 0);
}

// s_waitcnt imm: vmcnt bits[3:0]|[15:14], expcnt[6:4]=7 (no wait), lgkmcnt[11:8]=15 (no wait)
#define WVM4 0x0F74
#define WVM0 0x0F70

// C[m,n] = sum_{k in [z*KC,(z+1)*KC)} A[m,k]*B[n,k]  (A: MxK, B: NxK, bf16 row-major)
// Double-buffered LDS pipeline with raw barriers + manual vmcnt so next-tile
// global_load_lds stays in flight during current-tile MFMA.
// MODE 0: E = exp(scale[n]/(sqrt(max(x2[m]-2c+p2[n],0))+0.1)) -> bf16 NT store; row-sums atomically into aux3
// MODE 1: bf16 store of c + aux0[n]
// MODE 2: bf16 store of c
// MODE 3: bf16 NT store of c into partial slice z (Cv + z*M*N)
// SWZ 0: plain 2-D grid. SWZ 1: 2048 blocks, XCD owns 4-wide n-band (nXT=32).
// SWZ 2: 512 blocks, 4 n-tiles sharing an A-slice grouped per XCD, z=lin-derived.
template<int MODE, int SWZ>
__global__ void gemm_bt(const unsigned short* __restrict__ A,
                        const unsigned short* __restrict__ B,
                        void* __restrict__ Cv,
                        int M, int N, int K, int KC,
                        const float* __restrict__ aux0,
                        const float* __restrict__ aux1,
                        const float* __restrict__ aux2,
                        float* __restrict__ aux3)
{
  __shared__ unsigned short As[2][BM * BK];
  __shared__ unsigned short Bs[2][BN * BK];

  const int tid  = threadIdx.x;
  const int lane = tid & 63;
  const int wv   = tid >> 6;
  const int wm   = (wv >> 1) * 64;
  const int wn   = (wv & 1) * 64;
  const int l16  = lane & 15;
  const int quad = lane >> 4;

  int xt, yt, zt;
  if (SWZ == 0) {
    xt = blockIdx.x; yt = blockIdx.y; zt = 0;
  } else if (SWZ == 1) {
    const int lin = blockIdx.x;
    const int xcd = lin & 7, per = lin >> 3;
    xt = xcd * 4 + (per & 3); yt = per >> 2; zt = 0;
  } else {
    const int lin = blockIdx.x;
    const int xcd = lin & 7, per = lin >> 3;
    xt = per & 3;
    const int yz = ((per >> 2) << 3) | xcd;
    yt = yz & 63; zt = yz >> 6;
  }

  const int n0 = xt * BN;
  const int m0 = yt * BM;
  const int kbeg = zt * KC;

  f32x4 acc[4][4];
#pragma unroll
  for (int i = 0; i < 4; ++i)
#pragma unroll
    for (int j = 0; j < 4; ++j) {
      f32x4 z = {0.f, 0.f, 0.f, 0.f};
      acc[i][j] = z;
    }

  const int row0 = tid >> 2;
  const int col8 = (tid & 3) * 8;

  const unsigned short* Ag0 = A + (size_t)(m0 + row0) * K + col8 + kbeg;
  const unsigned short* Ag1 = A + (size_t)(m0 + row0 + 64) * K + col8 + kbeg;
  const unsigned short* Bg0 = B + (size_t)(n0 + row0) * K + col8 + kbeg;
  const unsigned short* Bg1 = B + (size_t)(n0 + row0 + 64) * K + col8 + kbeg;

  const int nk = KC >> 5;   // BK=32

  // prologue: tile 0 -> buffer 0
  gl_lds16(Ag0, &As[0][(size_t)tid * 8]);
  gl_lds16(Ag1, &As[0][(size_t)(tid + 256) * 8]);
  gl_lds16(Bg0, &Bs[0][(size_t)tid * 8]);
  gl_lds16(Bg1, &Bs[0][(size_t)(tid + 256) * 8]);

  for (int it = 0; it < nk; ++it) {
    const int cur = it & 1;
    const int nxt = cur ^ 1;
    __builtin_amdgcn_s_barrier();            // all waves done reading buf[nxt] (iter it-1)
    if (it + 1 < nk) {
      const int kc = (it + 1) << 5;
      gl_lds16(Ag0 + kc, &As[nxt][(size_t)tid * 8]);
      gl_lds16(Ag1 + kc, &As[nxt][(size_t)(tid + 256) * 8]);
      gl_lds16(Bg0 + kc, &Bs[nxt][(size_t)tid * 8]);
      gl_lds16(Bg1 + kc, &Bs[nxt][(size_t)(tid + 256) * 8]);
      __builtin_amdgcn_s_waitcnt(WVM4);      // my buf[cur] loads landed; 4 new in flight
    } else {
      __builtin_amdgcn_s_waitcnt(WVM0);
    }
    __builtin_amdgcn_s_barrier();            // everyone's buf[cur] loads visible

    bf16x8 af[4], bfr[4];
#pragma unroll
    for (int mi = 0; mi < 4; ++mi)
      af[mi] = *(const bf16x8*)&As[cur][(wm + mi * 16 + l16) * BK + quad * 8];
#pragma unroll
    for (int ni = 0; ni < 4; ++ni)
      bfr[ni] = *(const bf16x8*)&Bs[cur][(wn + ni * 16 + l16) * BK + quad * 8];
#pragma unroll
    for (int mi = 0; mi < 4; ++mi)
#pragma unroll
      for (int ni = 0; ni < 4; ++ni)
        acc[mi][ni] = __builtin_amdgcn_mfma_f32_16x16x32_bf16(af[mi], bfr[ni], acc[mi][ni], 0, 0, 0);
  }

  // ---- epilogue ----
  float p2v[4], scv[4], bnv[4];
  if (MODE == 0) {
#pragma unroll
    for (int ni = 0; ni < 4; ++ni) {
      const int n = n0 + wn + ni * 16 + l16;
      p2v[ni] = aux1[n];
      scv[ni] = aux2[n];
    }
  }
  if (MODE == 1) {
#pragma unroll
    for (int ni = 0; ni < 4; ++ni) bnv[ni] = aux0[n0 + wn + ni * 16 + l16];
  }

  unsigned short* Pz = nullptr;
  if (MODE == 3) Pz = (unsigned short*)Cv + (size_t)zt * (size_t)M * N;

#pragma unroll
  for (int mi = 0; mi < 4; ++mi) {
#pragma unroll
    for (int r = 0; r < 4; ++r) {
      const int m = m0 + wm + mi * 16 + quad * 4 + r;
      float rowa = 0.f;
      if (MODE == 0) rowa = aux0[m];
      float s = 0.f;
#pragma unroll
      for (int ni = 0; ni < 4; ++ni) {
        const int n = n0 + wn + ni * 16 + l16;
        float v = acc[mi][ni][r];
        if (MODE == 0) {
          float sq   = fmaxf(rowa - 2.0f * v + p2v[ni], 0.0f);
          float dist = sqrtf(sq);
          float e    = __expf(scv[ni] / (dist + 0.1f));
          unsigned short eb = f2bf(e);
          __builtin_nontemporal_store(eb, &((unsigned short*)Cv)[(size_t)m * N + n]);
          s += bf2f(eb);                 // sum exactly what we stored
        } else if (MODE == 1) {
          ((unsigned short*)Cv)[(size_t)m * N + n] = f2bf(v + bnv[ni]);
        } else if (MODE == 2) {
          ((unsigned short*)Cv)[(size_t)m * N + n] = f2bf(v);
        } else {
          __builtin_nontemporal_store(f2bf(v), &Pz[(size_t)m * N + n]);
        }
      }
      if (MODE == 0) {
        s += __shfl_down(s, 8);
        s += __shfl_down(s, 4);
        s += __shfl_down(s, 2);
        s += __shfl_down(s, 1);
        if (l16 == 0) unsafeAtomicAdd(&aux3[m], s);
      }
    }
  }
}

// Convert one 512-col fp32 row to bf16 + row sum-of-squares; one wave per row.
// Also zeroes denom[r] when given (piggyback to save a launch).
__global__ void prep_rows(const float* __restrict__ X, unsigned short* __restrict__ Xb,
                          float* __restrict__ nrm, float* __restrict__ denom) {
  const int lane = threadIdx.x & 63;
  const int wv   = threadIdx.x >> 6;
  const int r    = blockIdx.x * 4 + wv;
  const float4* row = (const float4*)(X + (size_t)r * 512);
  const float4 a = row[lane];
  const float4 b = row[lane + 64];
  ushort4 ua, ub;
  ua.x = f2bf(a.x); ua.y = f2bf(a.y); ua.z = f2bf(a.z); ua.w = f2bf(a.w);
  ub.x = f2bf(b.x); ub.y = f2bf(b.y); ub.z = f2bf(b.z); ub.w = f2bf(b.w);
  ushort4* orow = (ushort4*)(Xb + (size_t)r * 512);
  orow[lane] = ua;
  orow[lane + 64] = ub;
  float s = a.x*a.x + a.y*a.y + a.z*a.z + a.w*a.w
          + b.x*b.x + b.y*b.y + b.z*b.z + b.w*b.w;
#pragma unroll
  for (int off = 32; off > 0; off >>= 1) s += __shfl_down(s, off, 64);
  if (lane == 0) {
    nrm[r] = s;
    if (denom) denom[r] = 0.f;
  }
}

// convert w_v and w_o (512x512 each) to bf16
__global__ void prep_w(const float* __restrict__ wv_, const float* __restrict__ wo_,
                       unsigned short* __restrict__ wvb, unsigned short* __restrict__ wob) {
  int i = blockIdx.x * 256 + threadIdx.x;   // 65536 float4 each
  float4 a = ((const float4*)wv_)[i];
  float4 b = ((const float4*)wo_)[i];
  ushort4 ua, ub;
  ua.x = f2bf(a.x); ua.y = f2bf(a.y); ua.z = f2bf(a.z); ua.w = f2bf(a.w);
  ub.x = f2bf(b.x); ub.y = f2bf(b.y); ub.z = f2bf(b.z); ub.w = f2bf(b.w);
  ((ushort4*)wvb)[i] = ua;
  ((ushort4*)wob)[i] = ub;
}

// out[m,e] = (P0[m,e] + P1[m,e]) / denom[m] + b_o[e]   (P bf16, out fp32)
__global__ void reduce_out(const unsigned short* __restrict__ P,
                           const float* __restrict__ denom,
                           const float* __restrict__ b_o,
                           float* __restrict__ out) {
  const int i = blockIdx.x * 256 + threadIdx.x;   // over 1,048,576 float4s
  const int m = i >> 7;                            // 128 float4 per 512-col row
  const float rd = 1.0f / denom[m];
  const float4 b4 = ((const float4*)b_o)[i & 127];
  const ushort4 p0 = ((const ushort4*)P)[i];
  const ushort4 p1 = ((const ushort4*)P)[i + 1048576];
  float4 o;
  o.x = (bf2f(p0.x) + bf2f(p1.x)) * rd + b4.x;
  o.y = (bf2f(p0.y) + bf2f(p1.y)) * rd + b4.y;
  o.z = (bf2f(p0.z) + bf2f(p1.z)) * rd + b4.z;
  o.w = (bf2f(p0.w) + bf2f(p1.w)) * rd + b4.w;
  ((float4*)out)[i] = o;
}

extern "C" void kernel_launch(void* const* d_in, const int* in_sizes, int n_in,
                              void* d_out, int out_size, void* d_ws, size_t ws_size,
                              hipStream_t stream) {
  const float* x         = (const float*)d_in[0];
  const float* positions = (const float*)d_in[1];
  const float* scale     = (const float*)d_in[2];
  const float* w_v       = (const float*)d_in[3];
  const float* b_v       = (const float*)d_in[4];
  const float* w_o       = (const float*)d_in[5];
  const float* b_o       = (const float*)d_in[6];
  float* out = (float*)d_out;

  const int M = 8192, N = 4096, D = 512;

  // workspace layout (bytes); partials alias the dead xb/pb/w/val region
  char* base = (char*)d_ws;
  unsigned short* Eb    = (unsigned short*)(base + 0);          // 64 MB  [MODE-0 .. MODE-3]
  unsigned short* v2T   = (unsigned short*)(base + 67108864);   // 4 MB   [MODE-2 .. MODE-3]
  float*          denom = (float*)(base + 71303168);            // 32 KB
  float*          x2    = (float*)(base + 71335936);            // 32 KB
  float*          p2    = (float*)(base + 71368704);            // 16 KB
  char* base2 = base + 71385088;
  unsigned short* part  = (unsigned short*)base2;               // 16 MB  [MODE-3 .. reduce]
  unsigned short* xb    = (unsigned short*)base2;               // 8 MB   [prep .. MODE-0]
  unsigned short* pb    = (unsigned short*)(base2 + 8388608);   // 4 MB   [prep .. MODE-0]
  unsigned short* wvb   = (unsigned short*)(base2 + 12582912);  // 0.5 MB [prep .. MODE-1]
  unsigned short* wob   = (unsigned short*)(base2 + 13107200);  // 0.5 MB [prep .. MODE-2]
  unsigned short* val   = (unsigned short*)(base2 + 13631488);  // 4 MB   [MODE-1 .. MODE-2]

  // prep: bf16 conversions + row norms + denom zero
  prep_rows<<<M / 4, 256, 0, stream>>>(x, xb, x2, denom);
  prep_rows<<<N / 4, 256, 0, stream>>>(positions, pb, p2, nullptr);
  prep_w<<<256, 256, 0, stream>>>(w_v, w_o, wvb, wob);

  // values[n,d] = sum_k positions[n,k] w_v[d,k] + b_v[d]     (4096x512)
  gemm_bt<1, 0><<<dim3(D / BN, N / BM), 256, 0, stream>>>(
      pb, wvb, val, N, D, D, D, b_v, nullptr, nullptr, nullptr);

  // v2T[e,n] = sum_d w_o[e,d] values[n,d]                    (512x4096)
  gemm_bt<2, 0><<<dim3(N / BN, D / BM), 256, 0, stream>>>(
      wob, val, v2T, D, N, D, D, nullptr, nullptr, nullptr, nullptr);

  // E[m,n] = exp(scale[n]/(dist(m,n)+0.1)); denom[m] += row sums (atomic)
  gemm_bt<0, 1><<<2048, 256, 0, stream>>>(
      xb, pb, Eb, M, N, D, D, x2, p2, scale, denom);

  // part[z][m,e] = sum_{n in half z} E[m,n] v2T[e,n]   (split-K=2, bf16 partials)
  gemm_bt<3, 2><<<512, 256, 0, stream>>>(
      Eb, v2T, part, M, D, N, N / 2, nullptr, nullptr, nullptr, nullptr);

  // out = (part0 + part1)/denom + b_o
  reduce_out<<<4096, 256, 0, stream>>>(part, denom, b_o, out);
}

// Round 5
// 228.658 us; speedup vs baseline: 1.3442x; 1.0969x over previous
//
#include <hip/hip_runtime.h>
#include <cstdint>
#include <cstddef>

#define BM 128
#define BN 128
#define BK 32

using bf16x8 = __attribute__((ext_vector_type(8))) short;
using f32x4  = __attribute__((ext_vector_type(4))) float;

__device__ __forceinline__ unsigned short f2bf(float f) {
  unsigned int u = __builtin_bit_cast(unsigned int, f);
  u += 0x7FFFu + ((u >> 16) & 1u);   // round-to-nearest-even
  return (unsigned short)(u >> 16);
}
__device__ __forceinline__ float bf2f(unsigned int h16) {
  unsigned int u = h16 << 16;
  return __builtin_bit_cast(float, u);
}

__device__ __forceinline__ void gl_lds16(const void* g, void* l) {
  __builtin_amdgcn_global_load_lds(
      (const __attribute__((address_space(1))) unsigned int*)g,
      (__attribute__((address_space(3))) unsigned int*)l,
      16, 0, 0);
}

// s_waitcnt imm: vmcnt bits[3:0]|[15:14], expcnt[6:4]=7 (no wait), lgkmcnt[11:8]=15 (no wait)
#define WVM4 0x0F74
#define WVM0 0x0F70

// C[m,n] = sum_{k in [z*KC,(z+1)*KC)} A[m,k]*B[n,k]  (A: MxK, B: NxK, bf16 row-major)
// Double-buffered LDS + raw barriers + manual vmcnt (loads in flight across MFMA).
// LDS bank swizzle: chunk c holds global k-chunk (c&3)^((c>>3)&3) so the 16
// l16-lanes' ds_read_b128 base banks tile all 32 banks 2x (2-way = free).
// MODE 0: E = exp(scale[n]/(sqrt(max(x2[m]-2c+p2[n],0))+0.1)) -> bf16; row-sums atomic to aux3
// MODE 1: bf16 store of c + aux0[n]
// MODE 2: bf16 store of c
// MODE 3: bf16 store of c into partial slice z (Cv + z*M*N)
// SWZ 0: plain 2-D grid. SWZ 1: 2048 blocks, XCD owns 4-wide n-band.
// SWZ 2: 512 blocks, 4 n-tiles sharing an A-slice grouped per XCD, z=lin-derived.
template<int MODE, int SWZ>
__global__ void gemm_bt(const unsigned short* __restrict__ A,
                        const unsigned short* __restrict__ B,
                        void* __restrict__ Cv,
                        int M, int N, int K, int KC,
                        const float* __restrict__ aux0,
                        const float* __restrict__ aux1,
                        const float* __restrict__ aux2,
                        float* __restrict__ aux3)
{
  __shared__ unsigned short As[2][BM * BK];
  __shared__ unsigned short Bs[2][BN * BK];

  const int tid  = threadIdx.x;
  const int lane = tid & 63;
  const int wv   = tid >> 6;
  const int wm   = (wv >> 1) * 64;
  const int wn   = (wv & 1) * 64;
  const int l16  = lane & 15;
  const int quad = lane >> 4;
  const int sw   = (l16 >> 1) & 3;          // reader-side bank swizzle

  int xt, yt, zt;
  if (SWZ == 0) {
    xt = blockIdx.x; yt = blockIdx.y; zt = 0;
  } else if (SWZ == 1) {
    const int lin = blockIdx.x;
    const int xcd = lin & 7, per = lin >> 3;
    xt = xcd * 4 + (per & 3); yt = per >> 2; zt = 0;
  } else {
    const int lin = blockIdx.x;
    const int xcd = lin & 7, per = lin >> 3;
    xt = per & 3;
    const int yz = ((per >> 2) << 3) | xcd;
    yt = yz & 63; zt = yz >> 6;
  }

  const int n0 = xt * BN;
  const int m0 = yt * BM;
  const int kbeg = zt * KC;

  f32x4 acc[4][4];
#pragma unroll
  for (int i = 0; i < 4; ++i)
#pragma unroll
    for (int j = 0; j < 4; ++j) {
      f32x4 z = {0.f, 0.f, 0.f, 0.f};
      acc[i][j] = z;
    }

  // staging: LDS chunk c (= tid, tid+256) <- global k-chunk (c&3)^((c>>3)&3)
  const int row0 = tid >> 2;
  const int col8 = ((tid & 3) ^ ((tid >> 3) & 3)) * 8;

  const unsigned short* Ag0 = A + (size_t)(m0 + row0) * K + col8 + kbeg;
  const unsigned short* Ag1 = A + (size_t)(m0 + row0 + 64) * K + col8 + kbeg;
  const unsigned short* Bg0 = B + (size_t)(n0 + row0) * K + col8 + kbeg;
  const unsigned short* Bg1 = B + (size_t)(n0 + row0 + 64) * K + col8 + kbeg;

  const int nk = KC >> 5;   // BK=32

  // prologue: tile 0 -> buffer 0
  gl_lds16(Ag0, &As[0][(size_t)tid * 8]);
  gl_lds16(Ag1, &As[0][(size_t)(tid + 256) * 8]);
  gl_lds16(Bg0, &Bs[0][(size_t)tid * 8]);
  gl_lds16(Bg1, &Bs[0][(size_t)(tid + 256) * 8]);

  for (int it = 0; it < nk; ++it) {
    const int cur = it & 1;
    const int nxt = cur ^ 1;
    __builtin_amdgcn_s_barrier();            // all waves done reading buf[nxt] (iter it-1)
    if (it + 1 < nk) {
      const int kc = (it + 1) << 5;
      gl_lds16(Ag0 + kc, &As[nxt][(size_t)tid * 8]);
      gl_lds16(Ag1 + kc, &As[nxt][(size_t)(tid + 256) * 8]);
      gl_lds16(Bg0 + kc, &Bs[nxt][(size_t)tid * 8]);
      gl_lds16(Bg1 + kc, &Bs[nxt][(size_t)(tid + 256) * 8]);
      __builtin_amdgcn_s_waitcnt(WVM4);      // my buf[cur] loads landed; 4 new in flight
    } else {
      __builtin_amdgcn_s_waitcnt(WVM0);
    }
    __builtin_amdgcn_s_barrier();            // everyone's buf[cur] loads visible

    bf16x8 af[4], bfr[4];
#pragma unroll
    for (int mi = 0; mi < 4; ++mi) {
      const int r = wm + mi * 16 + l16;
      af[mi] = *(const bf16x8*)&As[cur][r * BK + (quad ^ sw) * 8];
    }
#pragma unroll
    for (int ni = 0; ni < 4; ++ni) {
      const int r = wn + ni * 16 + l16;
      bfr[ni] = *(const bf16x8*)&Bs[cur][r * BK + (quad ^ sw) * 8];
    }
#pragma unroll
    for (int mi = 0; mi < 4; ++mi)
#pragma unroll
      for (int ni = 0; ni < 4; ++ni)
        acc[mi][ni] = __builtin_amdgcn_mfma_f32_16x16x32_bf16(af[mi], bfr[ni], acc[mi][ni], 0, 0, 0);
  }

  // ---- epilogue ----
  float p2v[4], scv[4], bnv[4];
  if (MODE == 0) {
#pragma unroll
    for (int ni = 0; ni < 4; ++ni) {
      const int n = n0 + wn + ni * 16 + l16;
      p2v[ni] = aux1[n];
      scv[ni] = aux2[n] * 1.44269504088896f;   // fold log2(e): exp(x)=exp2(x*log2e)
    }
  }
  if (MODE == 1) {
#pragma unroll
    for (int ni = 0; ni < 4; ++ni) bnv[ni] = aux0[n0 + wn + ni * 16 + l16];
  }

  unsigned short* Pz = nullptr;
  if (MODE == 3) Pz = (unsigned short*)Cv + (size_t)zt * (size_t)M * N;

#pragma unroll
  for (int mi = 0; mi < 4; ++mi) {
#pragma unroll
    for (int r = 0; r < 4; ++r) {
      const int m = m0 + wm + mi * 16 + quad * 4 + r;
      float rowa = 0.f;
      if (MODE == 0) rowa = aux0[m];
      float s = 0.f;
#pragma unroll
      for (int ni = 0; ni < 4; ++ni) {
        const int n = n0 + wn + ni * 16 + l16;
        float v = acc[mi][ni][r];
        if (MODE == 0) {
          float sq   = fmaxf(rowa - 2.0f * v + p2v[ni], 0.0f);
          float dist = __builtin_amdgcn_sqrtf(sq);                    // v_sqrt_f32
          float e    = __builtin_amdgcn_exp2f(
                          scv[ni] * __builtin_amdgcn_rcpf(dist + 0.1f)); // v_rcp+v_exp
          unsigned short eb = f2bf(e);
          ((unsigned short*)Cv)[(size_t)m * N + n] = eb;
          s += bf2f(eb);                 // sum exactly what we stored
        } else if (MODE == 1) {
          ((unsigned short*)Cv)[(size_t)m * N + n] = f2bf(v + bnv[ni]);
        } else if (MODE == 2) {
          ((unsigned short*)Cv)[(size_t)m * N + n] = f2bf(v);
        } else {
          Pz[(size_t)m * N + n] = f2bf(v);
        }
      }
      if (MODE == 0) {
        s += __shfl_down(s, 8);
        s += __shfl_down(s, 4);
        s += __shfl_down(s, 2);
        s += __shfl_down(s, 1);
        if (l16 == 0) unsafeAtomicAdd(&aux3[m], s);
      }
    }
  }
}

// Convert one 512-col fp32 row to bf16 + row sum-of-squares; one wave per row.
// Also zeroes denom[r] when given (piggyback to save a launch).
__global__ void prep_rows(const float* __restrict__ X, unsigned short* __restrict__ Xb,
                          float* __restrict__ nrm, float* __restrict__ denom) {
  const int lane = threadIdx.x & 63;
  const int wv   = threadIdx.x >> 6;
  const int r    = blockIdx.x * 4 + wv;
  const float4* row = (const float4*)(X + (size_t)r * 512);
  const float4 a = row[lane];
  const float4 b = row[lane + 64];
  ushort4 ua, ub;
  ua.x = f2bf(a.x); ua.y = f2bf(a.y); ua.z = f2bf(a.z); ua.w = f2bf(a.w);
  ub.x = f2bf(b.x); ub.y = f2bf(b.y); ub.z = f2bf(b.z); ub.w = f2bf(b.w);
  ushort4* orow = (ushort4*)(Xb + (size_t)r * 512);
  orow[lane] = ua;
  orow[lane + 64] = ub;
  float s = a.x*a.x + a.y*a.y + a.z*a.z + a.w*a.w
          + b.x*b.x + b.y*b.y + b.z*b.z + b.w*b.w;
#pragma unroll
  for (int off = 32; off > 0; off >>= 1) s += __shfl_down(s, off, 64);
  if (lane == 0) {
    nrm[r] = s;
    if (denom) denom[r] = 0.f;
  }
}

// convert w_v and w_o (512x512 each) to bf16
__global__ void prep_w(const float* __restrict__ wv_, const float* __restrict__ wo_,
                       unsigned short* __restrict__ wvb, unsigned short* __restrict__ wob) {
  int i = blockIdx.x * 256 + threadIdx.x;   // 65536 float4 each
  float4 a = ((const float4*)wv_)[i];
  float4 b = ((const float4*)wo_)[i];
  ushort4 ua, ub;
  ua.x = f2bf(a.x); ua.y = f2bf(a.y); ua.z = f2bf(a.z); ua.w = f2bf(a.w);
  ub.x = f2bf(b.x); ub.y = f2bf(b.y); ub.z = f2bf(b.z); ub.w = f2bf(b.w);
  ((ushort4*)wvb)[i] = ua;
  ((ushort4*)wob)[i] = ub;
}

// out[m,e] = (P0[m,e] + P1[m,e]) / denom[m] + b_o[e]   (P bf16, out fp32)
__global__ void reduce_out(const unsigned short* __restrict__ P,
                           const float* __restrict__ denom,
                           const float* __restrict__ b_o,
                           float* __restrict__ out) {
  const int i = blockIdx.x * 256 + threadIdx.x;   // over 1,048,576 float4s
  const int m = i >> 7;                            // 128 float4 per 512-col row
  const float rd = 1.0f / denom[m];
  const float4 b4 = ((const float4*)b_o)[i & 127];
  const ushort4 p0 = ((const ushort4*)P)[i];
  const ushort4 p1 = ((const ushort4*)P)[i + 1048576];
  float4 o;
  o.x = (bf2f(p0.x) + bf2f(p1.x)) * rd + b4.x;
  o.y = (bf2f(p0.y) + bf2f(p1.y)) * rd + b4.y;
  o.z = (bf2f(p0.z) + bf2f(p1.z)) * rd + b4.z;
  o.w = (bf2f(p0.w) + bf2f(p1.w)) * rd + b4.w;
  ((float4*)out)[i] = o;
}

extern "C" void kernel_launch(void* const* d_in, const int* in_sizes, int n_in,
                              void* d_out, int out_size, void* d_ws, size_t ws_size,
                              hipStream_t stream) {
  const float* x         = (const float*)d_in[0];
  const float* positions = (const float*)d_in[1];
  const float* scale     = (const float*)d_in[2];
  const float* w_v       = (const float*)d_in[3];
  const float* b_v       = (const float*)d_in[4];
  const float* w_o       = (const float*)d_in[5];
  const float* b_o       = (const float*)d_in[6];
  float* out = (float*)d_out;

  const int M = 8192, N = 4096, D = 512;

  // workspace layout (bytes); partials alias the dead xb/pb/w/val region
  char* base = (char*)d_ws;
  unsigned short* Eb    = (unsigned short*)(base + 0);          // 64 MB  [MODE-0 .. MODE-3]
  unsigned short* v2T   = (unsigned short*)(base + 67108864);   // 4 MB   [MODE-2 .. MODE-3]
  float*          denom = (float*)(base + 71303168);            // 32 KB
  float*          x2    = (float*)(base + 71335936);            // 32 KB
  float*          p2    = (float*)(base + 71368704);            // 16 KB
  char* base2 = base + 71385088;
  unsigned short* part  = (unsigned short*)base2;               // 16 MB  [MODE-3 .. reduce]
  unsigned short* xb    = (unsigned short*)base2;               // 8 MB   [prep .. MODE-0]
  unsigned short* pb    = (unsigned short*)(base2 + 8388608);   // 4 MB   [prep .. MODE-0]
  unsigned short* wvb   = (unsigned short*)(base2 + 12582912);  // 0.5 MB [prep .. MODE-1]
  unsigned short* wob   = (unsigned short*)(base2 + 13107200);  // 0.5 MB [prep .. MODE-2]
  unsigned short* val   = (unsigned short*)(base2 + 13631488);  // 4 MB   [MODE-1 .. MODE-2]

  // prep: bf16 conversions + row norms + denom zero
  prep_rows<<<M / 4, 256, 0, stream>>>(x, xb, x2, denom);
  prep_rows<<<N / 4, 256, 0, stream>>>(positions, pb, p2, nullptr);
  prep_w<<<256, 256, 0, stream>>>(w_v, w_o, wvb, wob);

  // values[n,d] = sum_k positions[n,k] w_v[d,k] + b_v[d]     (4096x512)
  gemm_bt<1, 0><<<dim3(D / BN, N / BM), 256, 0, stream>>>(
      pb, wvb, val, N, D, D, D, b_v, nullptr, nullptr, nullptr);

  // v2T[e,n] = sum_d w_o[e,d] values[n,d]                    (512x4096)
  gemm_bt<2, 0><<<dim3(N / BN, D / BM), 256, 0, stream>>>(
      wob, val, v2T, D, N, D, D, nullptr, nullptr, nullptr, nullptr);

  // E[m,n] = exp(scale[n]/(dist(m,n)+0.1)); denom[m] += row sums (atomic)
  gemm_bt<0, 1><<<2048, 256, 0, stream>>>(
      xb, pb, Eb, M, N, D, D, x2, p2, scale, denom);

  // part[z][m,e] = sum_{n in half z} E[m,n] v2T[e,n]   (split-K=2, bf16 partials)
  gemm_bt<3, 2><<<512, 256, 0, stream>>>(
      Eb, v2T, part, M, D, N, N / 2, nullptr, nullptr, nullptr, nullptr);

  // out = (part0 + part1)/denom + b_o
  reduce_out<<<4096, 256, 0, stream>>>(part, denom, b_o, out);
}

// Round 6
// 224.848 us; speedup vs baseline: 1.3670x; 1.0169x over previous
//
#include <hip/hip_runtime.h>
#include <cstdint>
#include <cstddef>

using bf16x8 = __attribute__((ext_vector_type(8))) short;
using f32x4  = __attribute__((ext_vector_type(4))) float;

__device__ __forceinline__ unsigned short f2bf(float f) {
  unsigned int u = __builtin_bit_cast(unsigned int, f);
  u += 0x7FFFu + ((u >> 16) & 1u);   // round-to-nearest-even
  return (unsigned short)(u >> 16);
}
__device__ __forceinline__ float bf2f(unsigned int h16) {
  unsigned int u = h16 << 16;
  return __builtin_bit_cast(float, u);
}

__device__ __forceinline__ void gl_lds16(const void* g, void* l) {
  __builtin_amdgcn_global_load_lds(
      (const __attribute__((address_space(1))) unsigned int*)g,
      (__attribute__((address_space(3))) unsigned int*)l,
      16, 0, 0);
}

// C[m,n] = sum_{k in z-slice} A[m,k]*B[n,k]  (A: MxK, B: NxK, bf16 row-major)
// 3-stage LDS pipeline (prefetch distance 2), raw s_barrier + manual vmcnt.
// XOR bank swizzle on K-chunks (2-way = free).
// MODE 0: E=exp(scale[n]/(dist+0.1)) -> LDS-transposed coalesced bf16 store; row sums atomic to aux3
// MODE 2: bf16 store of c
// MODE 3: bf16 store of c into partial slice z
// SWZ 0: plain 2/3-D grid. SWZ 1: 2048 1-D, XCD owns 4-wide n-band.
// SWZ 3: 256 1-D, XCD owns 8 (m,z) groups x 4 e-tiles (E-slice read once/XCD).
template<int MODE, int SWZ, int WM, int WN>
__global__ __launch_bounds__(WM* WN * 64)
void gemm_bt(const unsigned short* __restrict__ A,
             const unsigned short* __restrict__ B,
             void* __restrict__ Cv,
             int M, int N, int K, int KC,
             const float* __restrict__ aux0,
             const float* __restrict__ aux1,
             const float* __restrict__ aux2,
             float* __restrict__ aux3)
{
  constexpr int THREADS = WM * WN * 64;
  constexpr int BMt = WM * 64, BNt = WN * 64;
  constexpr int NA = BMt * 4 / THREADS;   // A 16B-chunks per thread per stage
  constexpr int NB = BNt * 4 / THREADS;
  constexpr int L  = NA + NB;
  constexpr int ASZ = BMt * 32, BSZ = BNt * 32;

  __shared__ unsigned short smem[3 * (ASZ + BSZ)];
  unsigned short* As = smem;
  unsigned short* Bs = smem + 3 * ASZ;

  const int tid  = threadIdx.x;
  const int lane = tid & 63;
  const int wv   = tid >> 6;
  const int wm   = (wv / WN) * 64;
  const int wn   = (wv % WN) * 64;
  const int l16  = lane & 15;
  const int quad = lane >> 4;
  const int sw   = (l16 >> 1) & 3;

  int xt, yt, zt;
  if (SWZ == 0) {
    xt = blockIdx.x; yt = blockIdx.y; zt = 0;
  } else if (SWZ == 1) {
    const int lin = blockIdx.x;
    const int xcd = lin & 7, per = lin >> 3;
    xt = xcd * 4 + (per & 3); yt = per >> 2; zt = 0;
  } else {
    const int lin = blockIdx.x;           // 256 blocks
    const int xcd = lin & 7, i = lin >> 3;
    xt = i & 3;
    const int yz = xcd * 8 + (i >> 2);    // 8 (m,z) groups per XCD
    yt = yz & 31; zt = yz >> 5;
  }

  const int n0 = xt * BNt;
  const int m0 = yt * BMt;
  const int kbeg = zt * KC;

  f32x4 acc[4][4];
#pragma unroll
  for (int i = 0; i < 4; ++i)
#pragma unroll
    for (int j = 0; j < 4; ++j) {
      f32x4 z = {0.f, 0.f, 0.f, 0.f};
      acc[i][j] = z;
    }

  // staging descriptors: LDS chunk c <- global k-chunk (c&3)^((c>>3)&3)
  const unsigned short* gA[NA]; int lA[NA];
  const unsigned short* gB[NB]; int lB[NB];
#pragma unroll
  for (int i = 0; i < NA; ++i) {
    const int c = tid + i * THREADS;
    const int row = c >> 2, col = ((c & 3) ^ ((c >> 3) & 3)) * 8;
    gA[i] = A + (size_t)(m0 + row) * K + col + kbeg;
    lA[i] = c * 8;
  }
#pragma unroll
  for (int i = 0; i < NB; ++i) {
    const int c = tid + i * THREADS;
    const int row = c >> 2, col = ((c & 3) ^ ((c >> 3) & 3)) * 8;
    gB[i] = B + (size_t)(n0 + row) * K + col + kbeg;
    lB[i] = c * 8;
  }

  auto issue = [&](int st, int kc) {
#pragma unroll
    for (int i = 0; i < NA; ++i) gl_lds16(gA[i] + kc, &As[st * ASZ + lA[i]]);
#pragma unroll
    for (int i = 0; i < NB; ++i) gl_lds16(gB[i] + kc, &Bs[st * BSZ + lB[i]]);
  };

  const int nk = KC >> 5;   // BK = 32
  issue(0, 0);
  if (nk > 1) issue(1, 32);

  int cur = 0, pf = 2;
  for (int it = 0; it < nk; ++it) {
    __builtin_amdgcn_s_barrier();                 // buf[pf] (= it-1's) free to overwrite
    if (it + 2 < nk) {
      issue(pf, (it + 2) << 5);
      __builtin_amdgcn_s_waitcnt(0x0F70 | (2 * L));  // tile it landed, 2 stages in flight
    } else if (it + 1 < nk) {
      __builtin_amdgcn_s_waitcnt(0x0F70 | L);
    } else {
      __builtin_amdgcn_s_waitcnt(0x0F70);
    }
    __builtin_amdgcn_s_barrier();                 // everyone's tile-it data visible

    bf16x8 af[4], bfr[4];
#pragma unroll
    for (int mi = 0; mi < 4; ++mi)
      af[mi] = *(const bf16x8*)&As[cur * ASZ + (wm + mi * 16 + l16) * 32 + (quad ^ sw) * 8];
#pragma unroll
    for (int ni = 0; ni < 4; ++ni)
      bfr[ni] = *(const bf16x8*)&Bs[cur * BSZ + (wn + ni * 16 + l16) * 32 + (quad ^ sw) * 8];
#pragma unroll
    for (int mi = 0; mi < 4; ++mi)
#pragma unroll
      for (int ni = 0; ni < 4; ++ni)
        acc[mi][ni] = __builtin_amdgcn_mfma_f32_16x16x32_bf16(af[mi], bfr[ni], acc[mi][ni], 0, 0, 0);

    cur = (cur == 2) ? 0 : cur + 1;
    pf  = (pf == 2) ? 0 : pf + 1;
  }

  // ---- epilogue ----
  if constexpr (MODE == 0) {
    // (only instantiated with WM=WN=2, THREADS=256, BMt=BNt=128)
    float p2v[4], scv[4];
#pragma unroll
    for (int ni = 0; ni < 4; ++ni) {
      const int n = n0 + wn + ni * 16 + l16;
      p2v[ni] = aux1[n];
      scv[ni] = aux2[n] * 1.44269504088896f;   // fold log2(e)
    }
    __syncthreads();                            // done with K-loop LDS
    unsigned short* Es = smem;                  // 128 x (136-stride) bf16 tile
#pragma unroll
    for (int mi = 0; mi < 4; ++mi) {
#pragma unroll
      for (int r = 0; r < 4; ++r) {
        const int rowL = wm + mi * 16 + quad * 4 + r;
        const float rowa = aux0[m0 + rowL];
        float s = 0.f;
#pragma unroll
        for (int ni = 0; ni < 4; ++ni) {
          const int col = wn + ni * 16 + l16;
          const float v = acc[mi][ni][r];
          float sq   = fmaxf(rowa - 2.0f * v + p2v[ni], 0.0f);
          float dist = __builtin_amdgcn_sqrtf(sq);
          float e    = __builtin_amdgcn_exp2f(scv[ni] * __builtin_amdgcn_rcpf(dist + 0.1f));
          unsigned short eb = f2bf(e);
          Es[rowL * 136 + col] = eb;
          s += bf2f(eb);
        }
        s += __shfl_down(s, 8);
        s += __shfl_down(s, 4);
        s += __shfl_down(s, 2);
        s += __shfl_down(s, 1);
        if (l16 == 0) unsafeAtomicAdd(&aux3[m0 + rowL], s);
      }
    }
    __syncthreads();
    unsigned short* Eg = (unsigned short*)Cv;
#pragma unroll
    for (int j = 0; j < 8; ++j) {               // 128 rows x 16 chunks, coalesced 16B stores
      const int cid = j * 256 + tid;
      const int row = cid >> 4, c = cid & 15;
      bf16x8 v = *(const bf16x8*)&Es[row * 136 + c * 8];
      *(bf16x8*)&Eg[(size_t)(m0 + row) * N + n0 + c * 8] = v;
    }
  } else {
    unsigned short* Pz = (unsigned short*)Cv;
    if (MODE == 3) Pz += (size_t)zt * (size_t)M * N;
#pragma unroll
    for (int mi = 0; mi < 4; ++mi) {
#pragma unroll
      for (int r = 0; r < 4; ++r) {
        const int m = m0 + wm + mi * 16 + quad * 4 + r;
#pragma unroll
        for (int ni = 0; ni < 4; ++ni) {
          const int n = n0 + wn + ni * 16 + l16;
          Pz[(size_t)m * N + n] = f2bf(acc[mi][ni][r]);
        }
      }
    }
  }
}

// Convert one 512-col fp32 row to bf16 + row sum-of-squares; one wave per row.
__global__ void prep_rows(const float* __restrict__ X, unsigned short* __restrict__ Xb,
                          float* __restrict__ nrm, float* __restrict__ denom) {
  const int lane = threadIdx.x & 63;
  const int wv   = threadIdx.x >> 6;
  const int r    = blockIdx.x * 4 + wv;
  const float4* row = (const float4*)(X + (size_t)r * 512);
  const float4 a = row[lane];
  const float4 b = row[lane + 64];
  ushort4 ua, ub;
  ua.x = f2bf(a.x); ua.y = f2bf(a.y); ua.z = f2bf(a.z); ua.w = f2bf(a.w);
  ub.x = f2bf(b.x); ub.y = f2bf(b.y); ub.z = f2bf(b.z); ub.w = f2bf(b.w);
  ushort4* orow = (ushort4*)(Xb + (size_t)r * 512);
  orow[lane] = ua;
  orow[lane + 64] = ub;
  float s = a.x*a.x + a.y*a.y + a.z*a.z + a.w*a.w
          + b.x*b.x + b.y*b.y + b.z*b.z + b.w*b.w;
#pragma unroll
  for (int off = 32; off > 0; off >>= 1) s += __shfl_down(s, off, 64);
  if (lane == 0) {
    nrm[r] = s;
    if (denom) denom[r] = 0.f;
  }
}

// wo -> bf16 (row-major) and wv -> bf16 TRANSPOSED (wvT[k][d] = wv[d][k])
__global__ void prep_wT(const float* __restrict__ wv_, const float* __restrict__ wo_,
                        unsigned short* __restrict__ wvT, unsigned short* __restrict__ wob) {
  const int i = blockIdx.x * 256 + threadIdx.x;   // 65536
  float4 a = ((const float4*)wo_)[i];
  ushort4 ua;
  ua.x = f2bf(a.x); ua.y = f2bf(a.y); ua.z = f2bf(a.z); ua.w = f2bf(a.w);
  ((ushort4*)wob)[i] = ua;
  const int k = i >> 7, d4 = (i & 127) * 4;
  ushort4 t;
  t.x = f2bf(wv_[(size_t)(d4 + 0) * 512 + k]);
  t.y = f2bf(wv_[(size_t)(d4 + 1) * 512 + k]);
  t.z = f2bf(wv_[(size_t)(d4 + 2) * 512 + k]);
  t.w = f2bf(wv_[(size_t)(d4 + 3) * 512 + k]);
  ((ushort4*)wvT)[i] = t;                          // coalesced: k*128 + (i&127) == i
}

// bias2[e] = b_o[e] + dot(w_o[e,:], b_v)   (softmax rows sum to 1)
__global__ void prep_bias2(const float* __restrict__ wo_, const float* __restrict__ b_v,
                           const float* __restrict__ b_o, float* __restrict__ bias2) {
  const int lane = threadIdx.x & 63;
  const int e = blockIdx.x * 4 + (threadIdx.x >> 6);
  float s = 0.f;
#pragma unroll
  for (int j = 0; j < 8; ++j)
    s += wo_[(size_t)e * 512 + lane + j * 64] * b_v[lane + j * 64];
#pragma unroll
  for (int off = 32; off > 0; off >>= 1) s += __shfl_down(s, off, 64);
  if (lane == 0) bias2[e] = b_o[e] + s;
}

// out[m,e] = (P0[m,e] + P1[m,e]) / denom[m] + bias2[e]   (P bf16, out fp32)
__global__ void reduce_out(const unsigned short* __restrict__ P,
                           const float* __restrict__ denom,
                           const float* __restrict__ bias2,
                           float* __restrict__ out) {
  const int i = blockIdx.x * 256 + threadIdx.x;   // 1,048,576 float4s
  const int m = i >> 7;
  const float rd = 1.0f / denom[m];
  const float4 b4 = ((const float4*)bias2)[i & 127];
  const ushort4 p0 = ((const ushort4*)P)[i];
  const ushort4 p1 = ((const ushort4*)P)[i + 1048576];
  float4 o;
  o.x = (bf2f(p0.x) + bf2f(p1.x)) * rd + b4.x;
  o.y = (bf2f(p0.y) + bf2f(p1.y)) * rd + b4.y;
  o.z = (bf2f(p0.z) + bf2f(p1.z)) * rd + b4.z;
  o.w = (bf2f(p0.w) + bf2f(p1.w)) * rd + b4.w;
  ((float4*)out)[i] = o;
}

extern "C" void kernel_launch(void* const* d_in, const int* in_sizes, int n_in,
                              void* d_out, int out_size, void* d_ws, size_t ws_size,
                              hipStream_t stream) {
  const float* x         = (const float*)d_in[0];
  const float* positions = (const float*)d_in[1];
  const float* scale     = (const float*)d_in[2];
  const float* w_v       = (const float*)d_in[3];
  const float* b_v       = (const float*)d_in[4];
  const float* w_o       = (const float*)d_in[5];
  const float* b_o       = (const float*)d_in[6];
  float* out = (float*)d_out;

  const int M = 8192, N = 4096, D = 512;

  // workspace layout (bytes); bf16 staging buffers alias the partials region
  char* base = (char*)d_ws;
  unsigned short* Eb    = (unsigned short*)(base + 0);          // 64 MB
  unsigned short* v2T   = (unsigned short*)(base + 67108864);   // 4 MB
  float*          denom = (float*)(base + 71303168);            // 32 KB
  float*          x2    = (float*)(base + 71335936);            // 32 KB
  float*          p2    = (float*)(base + 71368704);            // 16 KB
  float*          bias2 = (float*)(base + 71385088);            // 2 KB
  char* base2 = base + 71387136;
  unsigned short* part  = (unsigned short*)base2;               // 16 MB [MODE-3 .. reduce]
  unsigned short* xb    = (unsigned short*)base2;               // 8 MB  [prep .. MODE-0]
  unsigned short* pb    = (unsigned short*)(base2 + 8388608);   // 4 MB  [prep .. MODE-0]
  unsigned short* wvT_b = (unsigned short*)(base2 + 12582912);  // 0.5 MB
  unsigned short* wo_b  = (unsigned short*)(base2 + 13107200);  // 0.5 MB
  unsigned short* W2b   = (unsigned short*)(base2 + 13631488);  // 0.5 MB

  prep_wT<<<256, 256, 0, stream>>>(w_v, w_o, wvT_b, wo_b);
  prep_bias2<<<128, 256, 0, stream>>>(w_o, b_v, b_o, bias2);
  prep_rows<<<M / 4, 256, 0, stream>>>(x, xb, x2, denom);
  prep_rows<<<N / 4, 256, 0, stream>>>(positions, pb, p2, nullptr);

  // W2[e,k] = sum_d wo[e,d] wv[d,k]
  gemm_bt<2, 0, 2, 2><<<dim3(4, 4), 256, 0, stream>>>(
      wo_b, wvT_b, W2b, 512, 512, 512, 512, nullptr, nullptr, nullptr, nullptr);

  // v2T[e,n] = sum_k W2[e,k] p[n,k]
  gemm_bt<2, 0, 2, 2><<<dim3(32, 4), 256, 0, stream>>>(
      W2b, pb, v2T, 512, 4096, 512, 512, nullptr, nullptr, nullptr, nullptr);

  // E[m,n] = exp(scale[n]/(dist+0.1)); denom[m] += row sums
  gemm_bt<0, 1, 2, 2><<<2048, 256, 0, stream>>>(
      xb, pb, Eb, M, N, D, D, x2, p2, scale, denom);

  // part[z][m,e] = sum_{n in half z} E[m,n] v2T[e,n]   (256x128 tiles, 512 thr)
  gemm_bt<3, 3, 4, 2><<<256, 512, 0, stream>>>(
      Eb, v2T, part, M, D, N, N / 2, nullptr, nullptr, nullptr, nullptr);

  // out = (part0 + part1)/denom + bias2
  reduce_out<<<4096, 256, 0, stream>>>(part, denom, bias2, out);
}